// Round 1
// baseline (1623.746 us; speedup 1.0000x reference)
//
#include <hip/hip_runtime.h>

// GCN layer: out = ReLU(BN(GCNConv(x) + x@skip_W))
// Restructured: aggregate in IN_DIM (64), single fused GEMM [N,128]@[128,128].

constexpr int N_NODES = 100000;
constexpr int E_EDGES = 1600000;
constexpr int IN_DIM  = 64;
constexpr int OUT_DIM = 128;

// ws layout (float offsets)
constexpr size_t WS_DEG   = 0;                              // N floats: deg -> dinv in place
constexpr size_t WS_AGG   = 100096;                         // N*64 floats: edge aggregate -> u in place
constexpr size_t WS_STATS = WS_AGG + (size_t)N_NODES * 64;  // sum[128], sumsq[128]
constexpr size_t WS_SCALE = WS_STATS + 256;                 // scale[128], shift[128]
// zero from 0 through stats
constexpr size_t WS_ZERO_BYTES = (WS_STATS + 256) * 4;

__global__ void k_deg(const int* __restrict__ col, float* __restrict__ deg) {
    int i = blockIdx.x * blockDim.x + threadIdx.x;
    if (i < E_EDGES) atomicAdd(&deg[col[i]], 1.0f);
}

__global__ void k_dinv(float* __restrict__ deg) {
    int i = blockIdx.x * blockDim.x + threadIdx.x;
    if (i < N_NODES) deg[i] = rsqrtf(deg[i] + 1.0f);  // +1 self-loop
}

// 16 threads per edge; each thread: float4 gather from x, scale by dinv[src], 4 atomic adds.
__global__ void k_scatter(const int* __restrict__ row, const int* __restrict__ col,
                          const float* __restrict__ x, const float* __restrict__ dinv,
                          float* __restrict__ agg) {
    long long t = (long long)blockIdx.x * blockDim.x + threadIdx.x;
    if (t >= (long long)E_EDGES * 16) return;
    int e = (int)(t >> 4);
    int q = (int)(t & 15);
    int r = row[e];
    int c = col[e];
    float s = dinv[r];
    float4 v = ((const float4*)x)[(size_t)r * 16 + q];
    float* dst = &agg[(size_t)c * 64 + q * 4];
    atomicAdd(dst + 0, v.x * s);
    atomicAdd(dst + 1, v.y * s);
    atomicAdd(dst + 2, v.z * s);
    atomicAdd(dst + 3, v.w * s);
}

// u[i] = dinv[i] * (x[i]*dinv[i] + agg[i]), in place over agg.
__global__ void k_u(const float* __restrict__ x, const float* __restrict__ dinv,
                    float* __restrict__ agg) {
    int t = blockIdx.x * blockDim.x + threadIdx.x;
    if (t >= N_NODES * 16) return;
    int i = t >> 4;
    float di = dinv[i];
    float4 xv = ((const float4*)x)[t];
    float4 av = ((float4*)agg)[t];
    float4 r;
    r.x = di * (xv.x * di + av.x);
    r.y = di * (xv.y * di + av.y);
    r.z = di * (xv.z * di + av.z);
    r.w = di * (xv.w * di + av.w);
    ((float4*)agg)[t] = r;
}

// Fused GEMM: out_pre[i][j] = [u|x][i][:] dot [W;skipW][:][j] + bias[j]
// Block: 256 threads -> 128 rows x 128 cols, 8x8 per-thread register tile.
// Also accumulates per-column sum/sumsq (block-reduced, then atomics).
#define BK 32
__global__ __launch_bounds__(256) void k_gemm(
    const float* __restrict__ u, const float* __restrict__ x,
    const float* __restrict__ W, const float* __restrict__ skipW,
    const float* __restrict__ bias, float* __restrict__ out,
    float* __restrict__ stats) {
    __shared__ float As[BK][128];  // [k][row] 16KB
    __shared__ float Bs[BK][128];  // [k][col] 16KB

    int ib = blockIdx.x * 128;
    int tid = threadIdx.x;
    int tx = tid & 15;   // col group: cols tx*8 .. tx*8+7
    int ty = tid >> 4;   // row group: rows ty*8 .. ty*8+7

    float acc[8][8];
#pragma unroll
    for (int a = 0; a < 8; ++a)
#pragma unroll
        for (int b = 0; b < 8; ++b) acc[a][b] = 0.0f;

    for (int kc = 0; kc < 128; kc += BK) {
        const float* asrc = (kc < 64) ? u : x;
        const float* bsrc = (kc < 64) ? W : skipW;
        int ksrc = (kc < 64) ? kc : (kc - 64);

        // Stage A: 32k x 128rows; thread loads 4x float4 along k, stores transposed.
#pragma unroll
        for (int p = 0; p < 4; ++p) {
            int i  = p * 32 + (tid >> 3);   // 0..127 local row
            int kk = (tid & 7) * 4;         // 0..28
            float4 v = make_float4(0.f, 0.f, 0.f, 0.f);
            int gi = ib + i;
            if (gi < N_NODES)
                v = *(const float4*)&asrc[(size_t)gi * 64 + ksrc + kk];
            As[kk + 0][i] = v.x;
            As[kk + 1][i] = v.y;
            As[kk + 2][i] = v.z;
            As[kk + 3][i] = v.w;
        }
        // Stage B: 32k x 128cols; thread loads 16 floats of one k-row.
        {
            int kk = tid >> 3;
            int j0 = (tid & 7) * 16;
            const float* bp = &bsrc[(size_t)(ksrc + kk) * 128 + j0];
#pragma unroll
            for (int q = 0; q < 4; ++q)
                *(float4*)&Bs[kk][j0 + q * 4] = *(const float4*)&bp[q * 4];
        }
        __syncthreads();

#pragma unroll
        for (int kk = 0; kk < BK; ++kk) {
            float a[8], b[8];
            *(float4*)&a[0] = *(float4*)&As[kk][ty * 8];
            *(float4*)&a[4] = *(float4*)&As[kk][ty * 8 + 4];
            *(float4*)&b[0] = *(float4*)&Bs[kk][tx * 8];
            *(float4*)&b[4] = *(float4*)&Bs[kk][tx * 8 + 4];
#pragma unroll
            for (int ii = 0; ii < 8; ++ii)
#pragma unroll
                for (int jj = 0; jj < 8; ++jj) acc[ii][jj] += a[ii] * b[jj];
        }
        __syncthreads();
    }

    // Epilogue: +bias, write pre-BN to out, local stats.
    float bias8[8];
    *(float4*)&bias8[0] = *(const float4*)&bias[tx * 8];
    *(float4*)&bias8[4] = *(const float4*)&bias[tx * 8 + 4];

    float lsum[8], lsq[8];
#pragma unroll
    for (int jj = 0; jj < 8; ++jj) { lsum[jj] = 0.f; lsq[jj] = 0.f; }

#pragma unroll
    for (int ii = 0; ii < 8; ++ii) {
        int gi = ib + ty * 8 + ii;
        if (gi < N_NODES) {
            float vals[8];
#pragma unroll
            for (int jj = 0; jj < 8; ++jj) {
                float v = acc[ii][jj] + bias8[jj];
                vals[jj] = v;
                lsum[jj] += v;
                lsq[jj] += v * v;
            }
            *(float4*)&out[(size_t)gi * 128 + tx * 8]     = *(float4*)&vals[0];
            *(float4*)&out[(size_t)gi * 128 + tx * 8 + 4] = *(float4*)&vals[4];
        }
    }

    // Block-level stats reduction (reuse As/Bs as scratch: 256*8 floats each).
    float* sred = &As[0][0];
    float* qred = &Bs[0][0];
#pragma unroll
    for (int jj = 0; jj < 8; ++jj) {
        sred[tid * 8 + jj] = lsum[jj];
        qred[tid * 8 + jj] = lsq[jj];
    }
    __syncthreads();
    if (tid < 128) {
        int j = tid;
        int txg = j >> 3, jj = j & 7;
        float s = 0.f, q = 0.f;
#pragma unroll
        for (int t2 = 0; t2 < 16; ++t2) {
            int st = t2 * 16 + txg;
            s += sred[st * 8 + jj];
            q += qred[st * 8 + jj];
        }
        atomicAdd(&stats[j], s);
        atomicAdd(&stats[128 + j], q);
    }
}

__global__ void k_finalize(const float* __restrict__ stats,
                           const float* __restrict__ gamma,
                           const float* __restrict__ beta,
                           float* __restrict__ scaleshift) {
    int j = threadIdx.x;
    if (j < 128) {
        float mean = stats[j] * (1.0f / N_NODES);
        float var  = stats[128 + j] * (1.0f / N_NODES) - mean * mean;
        float sc   = gamma[j] * rsqrtf(var + 1e-5f);
        scaleshift[j]       = sc;
        scaleshift[128 + j] = beta[j] - mean * sc;
    }
}

__global__ void k_apply(float* __restrict__ out, const float* __restrict__ scaleshift) {
    int t = blockIdx.x * blockDim.x + threadIdx.x;
    if (t >= N_NODES * 32) return;  // N*128/4 float4s
    int j4 = t & 31;
    float4 v  = ((float4*)out)[t];
    float4 sc = ((const float4*)scaleshift)[j4];
    float4 sh = ((const float4*)(scaleshift + 128))[j4];
    v.x = fmaxf(fmaf(v.x, sc.x, sh.x), 0.f);
    v.y = fmaxf(fmaf(v.y, sc.y, sh.y), 0.f);
    v.z = fmaxf(fmaf(v.z, sc.z, sh.z), 0.f);
    v.w = fmaxf(fmaf(v.w, sc.w, sh.w), 0.f);
    ((float4*)out)[t] = v;
}

extern "C" void kernel_launch(void* const* d_in, const int* in_sizes, int n_in,
                              void* d_out, int out_size, void* d_ws, size_t ws_size,
                              hipStream_t stream) {
    const float* x      = (const float*)d_in[0];
    const int*   eidx   = (const int*)d_in[1];   // [2, E] flat: row then col
    const float* W      = (const float*)d_in[2];
    const float* bias   = (const float*)d_in[3];
    const float* skipW  = (const float*)d_in[4];
    const float* gamma  = (const float*)d_in[5];
    const float* beta   = (const float*)d_in[6];
    float* out = (float*)d_out;
    float* ws  = (float*)d_ws;

    const int* row = eidx;
    const int* col = eidx + E_EDGES;

    float* deg        = ws + WS_DEG;    // becomes dinv
    float* agg        = ws + WS_AGG;    // becomes u
    float* stats      = ws + WS_STATS;
    float* scaleshift = ws + WS_SCALE;

    hipMemsetAsync(d_ws, 0, WS_ZERO_BYTES, stream);

    k_deg<<<(E_EDGES + 255) / 256, 256, 0, stream>>>(col, deg);
    k_dinv<<<(N_NODES + 255) / 256, 256, 0, stream>>>(deg);
    {
        long long tot = (long long)E_EDGES * 16;
        int blocks = (int)((tot + 255) / 256);
        k_scatter<<<blocks, 256, 0, stream>>>(row, col, x, deg, agg);
    }
    k_u<<<(N_NODES * 16 + 255) / 256, 256, 0, stream>>>(x, deg, agg);
    {
        int blocks = (N_NODES + 127) / 128;  // 782
        k_gemm<<<blocks, 256, 0, stream>>>(agg, x, W, skipW, bias, out, stats);
    }
    k_finalize<<<1, 128, 0, stream>>>(stats, gamma, beta, scaleshift);
    k_apply<<<(N_NODES * 32 + 255) / 256, 256, 0, stream>>>(out, scaleshift);
}

// Round 2
// 435.369 us; speedup vs baseline: 3.7296x; 3.7296x over previous
//
#include <hip/hip_runtime.h>

// GCN layer: out = ReLU(BN(GCNConv(x) + x@skip_W))
// R2: scatter-atomics -> on-device CSR build + gather aggregation.
// Aggregate in IN_DIM (64), single fused GEMM [N,128]@[128,128].

constexpr int N_NODES = 100000;
constexpr int E_EDGES = 1600000;
constexpr int NB      = (N_NODES + 255) / 256;   // 391 scan blocks

// ws layout (4-byte element offsets)
constexpr size_t OFF_CNT    = 0;         // N ints (zeroed)
constexpr size_t OFF_STATS  = 100096;    // 256 floats (zeroed)
constexpr size_t OFF_SCALE  = 100352;    // 256 floats
constexpr size_t OFF_DINV   = 100608;    // N floats
constexpr size_t OFF_ROWPTR = 200704;    // N ints (inclusive scan -> exclusive in place)
constexpr size_t OFF_CURSOR = 300800;    // N ints
constexpr size_t OFF_BSUMS  = 400896;    // 512 ints
constexpr size_t OFF_BOFFS  = 401408;    // 512 ints
constexpr size_t OFF_CSR    = 401920;    // E ints
constexpr size_t OFF_AGG    = 2001920;   // N*64 floats (u)
constexpr size_t WS_ZERO_BYTES = (100352) * 4;   // cnt + pad + stats

__global__ void k_count(const int* __restrict__ col, int* __restrict__ cnt) {
    int e = blockIdx.x * blockDim.x + threadIdx.x;
    if (e < E_EDGES) atomicAdd(&cnt[col[e]], 1);
}

// block-level inclusive scan of cnt; also computes dinv.
__global__ __launch_bounds__(256) void k_scan1(const int* __restrict__ cnt,
                                               float* __restrict__ dinv,
                                               int* __restrict__ incl,
                                               int* __restrict__ bsums) {
    __shared__ int lds[256];
    int tid = threadIdx.x;
    int i = blockIdx.x * 256 + tid;
    int v = (i < N_NODES) ? cnt[i] : 0;
    if (i < N_NODES) dinv[i] = rsqrtf((float)v + 1.0f);  // +1 self loop
    lds[tid] = v;
    __syncthreads();
    int val = v;
#pragma unroll
    for (int off = 1; off < 256; off <<= 1) {
        int add = (tid >= off) ? lds[tid - off] : 0;
        __syncthreads();
        val += add;
        lds[tid] = val;
        __syncthreads();
    }
    if (i < N_NODES) incl[i] = val;
    if (tid == 255) bsums[blockIdx.x] = val;
}

// single-block scan of block sums -> exclusive block offsets.
__global__ __launch_bounds__(512) void k_scan2(const int* __restrict__ bsums,
                                               int* __restrict__ boffs) {
    __shared__ int lds[512];
    int tid = threadIdx.x;
    int v = (tid < NB) ? bsums[tid] : 0;
    lds[tid] = v;
    __syncthreads();
    int val = v;
#pragma unroll
    for (int off = 1; off < 512; off <<= 1) {
        int add = (tid >= off) ? lds[tid - off] : 0;
        __syncthreads();
        val += add;
        lds[tid] = val;
        __syncthreads();
    }
    if (tid < NB) boffs[tid] = val - v;  // exclusive
}

// finalize exclusive rowptr (in place over incl) and init cursor.
__global__ void k_scan3(const int* __restrict__ cnt, int* __restrict__ rowptr,
                        int* __restrict__ cursor, const int* __restrict__ boffs) {
    int i = blockIdx.x * blockDim.x + threadIdx.x;
    if (i < N_NODES) {
        int ex = rowptr[i] - cnt[i] + boffs[i >> 8];
        rowptr[i] = ex;
        cursor[i] = ex;
    }
}

__global__ void k_place(const int* __restrict__ row, const int* __restrict__ col,
                        int* __restrict__ cursor, int* __restrict__ csr) {
    int e = blockIdx.x * blockDim.x + threadIdx.x;
    if (e < E_EDGES) {
        int c = col[e];
        int p = atomicAdd(&cursor[c], 1);
        csr[p] = row[e];
    }
}

// Gather-aggregate: 16 lanes per node, each owns a float4 chunk.
// u[c] = dinv[c] * ( x[c]*dinv[c] + sum_{r->c} x[r]*dinv[r] )
__global__ __launch_bounds__(256) void k_agg(const float* __restrict__ x,
                                             const float* __restrict__ dinv,
                                             const int* __restrict__ rowptr,
                                             const int* __restrict__ cursor,
                                             const int* __restrict__ csr,
                                             float* __restrict__ agg) {
    int t = blockIdx.x * blockDim.x + threadIdx.x;
    if (t >= N_NODES * 16) return;
    int c = t >> 4;
    int q = t & 15;
    float dc = dinv[c];
    float4 xv = ((const float4*)x)[(size_t)c * 16 + q];
    float4 acc;
    acc.x = xv.x * dc; acc.y = xv.y * dc; acc.z = xv.z * dc; acc.w = xv.w * dc;
    int i0 = rowptr[c], i1 = cursor[c];
    for (int i = i0; i < i1; ++i) {
        int s = csr[i];
        float ds = dinv[s];
        float4 v = ((const float4*)x)[(size_t)s * 16 + q];
        acc.x += v.x * ds; acc.y += v.y * ds;
        acc.z += v.z * ds; acc.w += v.w * ds;
    }
    acc.x *= dc; acc.y *= dc; acc.z *= dc; acc.w *= dc;
    ((float4*)agg)[t] = acc;
}

// Fused GEMM: out_pre[i][j] = [u|x][i][:] dot [W;skipW][:][j] + bias[j]
// 256 threads -> 128x128 tile, 8x8 register tiles; also per-column stats.
#define BK 32
__global__ __launch_bounds__(256) void k_gemm(
    const float* __restrict__ u, const float* __restrict__ x,
    const float* __restrict__ W, const float* __restrict__ skipW,
    const float* __restrict__ bias, float* __restrict__ out,
    float* __restrict__ stats) {
    __shared__ float As[BK][128];
    __shared__ float Bs[BK][128];

    int ib = blockIdx.x * 128;
    int tid = threadIdx.x;
    int tx = tid & 15;
    int ty = tid >> 4;

    float acc[8][8];
#pragma unroll
    for (int a = 0; a < 8; ++a)
#pragma unroll
        for (int b = 0; b < 8; ++b) acc[a][b] = 0.0f;

    for (int kc = 0; kc < 128; kc += BK) {
        const float* asrc = (kc < 64) ? u : x;
        const float* bsrc = (kc < 64) ? W : skipW;
        int ksrc = (kc < 64) ? kc : (kc - 64);

#pragma unroll
        for (int p = 0; p < 4; ++p) {
            int i  = p * 32 + (tid >> 3);
            int kk = (tid & 7) * 4;
            float4 v = make_float4(0.f, 0.f, 0.f, 0.f);
            int gi = ib + i;
            if (gi < N_NODES)
                v = *(const float4*)&asrc[(size_t)gi * 64 + ksrc + kk];
            As[kk + 0][i] = v.x;
            As[kk + 1][i] = v.y;
            As[kk + 2][i] = v.z;
            As[kk + 3][i] = v.w;
        }
        {
            int kk = tid >> 3;
            int j0 = (tid & 7) * 16;
            const float* bp = &bsrc[(size_t)(ksrc + kk) * 128 + j0];
#pragma unroll
            for (int q = 0; q < 4; ++q)
                *(float4*)&Bs[kk][j0 + q * 4] = *(const float4*)&bp[q * 4];
        }
        __syncthreads();

#pragma unroll
        for (int kk = 0; kk < BK; ++kk) {
            float a[8], b[8];
            *(float4*)&a[0] = *(float4*)&As[kk][ty * 8];
            *(float4*)&a[4] = *(float4*)&As[kk][ty * 8 + 4];
            *(float4*)&b[0] = *(float4*)&Bs[kk][tx * 8];
            *(float4*)&b[4] = *(float4*)&Bs[kk][tx * 8 + 4];
#pragma unroll
            for (int ii = 0; ii < 8; ++ii)
#pragma unroll
                for (int jj = 0; jj < 8; ++jj) acc[ii][jj] += a[ii] * b[jj];
        }
        __syncthreads();
    }

    float bias8[8];
    *(float4*)&bias8[0] = *(const float4*)&bias[tx * 8];
    *(float4*)&bias8[4] = *(const float4*)&bias[tx * 8 + 4];

    float lsum[8], lsq[8];
#pragma unroll
    for (int jj = 0; jj < 8; ++jj) { lsum[jj] = 0.f; lsq[jj] = 0.f; }

#pragma unroll
    for (int ii = 0; ii < 8; ++ii) {
        int gi = ib + ty * 8 + ii;
        if (gi < N_NODES) {
            float vals[8];
#pragma unroll
            for (int jj = 0; jj < 8; ++jj) {
                float v = acc[ii][jj] + bias8[jj];
                vals[jj] = v;
                lsum[jj] += v;
                lsq[jj] += v * v;
            }
            *(float4*)&out[(size_t)gi * 128 + tx * 8]     = *(float4*)&vals[0];
            *(float4*)&out[(size_t)gi * 128 + tx * 8 + 4] = *(float4*)&vals[4];
        }
    }

    float* sred = &As[0][0];
    float* qred = &Bs[0][0];
#pragma unroll
    for (int jj = 0; jj < 8; ++jj) {
        sred[tid * 8 + jj] = lsum[jj];
        qred[tid * 8 + jj] = lsq[jj];
    }
    __syncthreads();
    if (tid < 128) {
        int j = tid;
        int txg = j >> 3, jj = j & 7;
        float s = 0.f, q = 0.f;
#pragma unroll
        for (int t2 = 0; t2 < 16; ++t2) {
            int st = t2 * 16 + txg;
            s += sred[st * 8 + jj];
            q += qred[st * 8 + jj];
        }
        atomicAdd(&stats[j], s);
        atomicAdd(&stats[128 + j], q);
    }
}

__global__ void k_finalize(const float* __restrict__ stats,
                           const float* __restrict__ gamma,
                           const float* __restrict__ beta,
                           float* __restrict__ scaleshift) {
    int j = threadIdx.x;
    if (j < 128) {
        float mean = stats[j] * (1.0f / N_NODES);
        float var  = stats[128 + j] * (1.0f / N_NODES) - mean * mean;
        float sc   = gamma[j] * rsqrtf(var + 1e-5f);
        scaleshift[j]       = sc;
        scaleshift[128 + j] = beta[j] - mean * sc;
    }
}

__global__ void k_apply(float* __restrict__ out, const float* __restrict__ scaleshift) {
    int t = blockIdx.x * blockDim.x + threadIdx.x;
    if (t >= N_NODES * 32) return;
    int j4 = t & 31;
    float4 v  = ((float4*)out)[t];
    float4 sc = ((const float4*)scaleshift)[j4];
    float4 sh = ((const float4*)(scaleshift + 128))[j4];
    v.x = fmaxf(fmaf(v.x, sc.x, sh.x), 0.f);
    v.y = fmaxf(fmaf(v.y, sc.y, sh.y), 0.f);
    v.z = fmaxf(fmaf(v.z, sc.z, sh.z), 0.f);
    v.w = fmaxf(fmaf(v.w, sc.w, sh.w), 0.f);
    ((float4*)out)[t] = v;
}

extern "C" void kernel_launch(void* const* d_in, const int* in_sizes, int n_in,
                              void* d_out, int out_size, void* d_ws, size_t ws_size,
                              hipStream_t stream) {
    const float* x      = (const float*)d_in[0];
    const int*   eidx   = (const int*)d_in[1];
    const float* W      = (const float*)d_in[2];
    const float* bias   = (const float*)d_in[3];
    const float* skipW  = (const float*)d_in[4];
    const float* gamma  = (const float*)d_in[5];
    const float* beta   = (const float*)d_in[6];
    float* out = (float*)d_out;
    float* ws  = (float*)d_ws;

    const int* row = eidx;
    const int* col = eidx + E_EDGES;

    int*   cnt        = (int*)(ws + OFF_CNT);
    float* stats      = ws + OFF_STATS;
    float* scaleshift = ws + OFF_SCALE;
    float* dinv       = ws + OFF_DINV;
    int*   rowptr     = (int*)(ws + OFF_ROWPTR);
    int*   cursor     = (int*)(ws + OFF_CURSOR);
    int*   bsums      = (int*)(ws + OFF_BSUMS);
    int*   boffs      = (int*)(ws + OFF_BOFFS);
    int*   csr        = (int*)(ws + OFF_CSR);
    float* agg        = ws + OFF_AGG;

    hipMemsetAsync(d_ws, 0, WS_ZERO_BYTES, stream);

    k_count<<<(E_EDGES + 255) / 256, 256, 0, stream>>>(col, cnt);
    k_scan1<<<NB, 256, 0, stream>>>(cnt, dinv, rowptr, bsums);
    k_scan2<<<1, 512, 0, stream>>>(bsums, boffs);
    k_scan3<<<NB, 256, 0, stream>>>(cnt, rowptr, cursor, boffs);
    k_place<<<(E_EDGES + 255) / 256, 256, 0, stream>>>(row, col, cursor, csr);
    k_agg<<<(N_NODES * 16 + 255) / 256, 256, 0, stream>>>(x, dinv, rowptr, cursor, csr, agg);
    {
        int blocks = (N_NODES + 127) / 128;
        k_gemm<<<blocks, 256, 0, stream>>>(agg, x, W, skipW, bias, out, stats);
    }
    k_finalize<<<1, 128, 0, stream>>>(stats, gamma, beta, scaleshift);
    k_apply<<<(N_NODES * 32 + 255) / 256, 256, 0, stream>>>(out, scaleshift);
}

// Round 3
// 293.821 us; speedup vs baseline: 5.5263x; 1.4817x over previous
//
#include <hip/hip_runtime.h>

// GCN layer: out = ReLU(BN(GCNConv(x) + x@skip_W))
// R3: atomic CSR build -> two-level counting sort (no global atomics).
// Aggregate in IN_DIM (64), single fused GEMM [N,128]@[128,128].

constexpr int N_NODES = 100000;
constexpr int E_EDGES = 1600000;

constexpr int BUCK_SHIFT = 7;                    // 128 nodes per bucket
constexpr int NBUCK   = (N_NODES + 127) / 128;   // 782
constexpr int NBUCK_P = 784;                     // padded
constexpr int CHUNK   = 8192;                    // edges per hist/scatter block
constexpr int NCHUNK  = (E_EDGES + CHUNK - 1) / CHUNK;  // 196
constexpr int SORT_CAP = 4096;                   // max edges per bucket (mean 2048, sd ~45)

// ws layout (4-byte element offsets)
constexpr size_t OFF_STATS  = 0;         // 256 floats (zeroed)
constexpr size_t OFF_SCALE  = 256;       // 256 floats
constexpr size_t OFF_DINV   = 512;       // N floats
constexpr size_t OFF_ROWPTR = 100608;    // N+1 ints
constexpr size_t OFF_BASE   = 200704;    // NBUCK+1 ints (padded region 784)
constexpr size_t OFF_GHIST  = 201536;    // NCHUNK*NBUCK_P ints = 153664
constexpr size_t OFF_BINNED = 355264;    // E ints (packed edges; csr aliases in place)
constexpr size_t OFF_AGG    = 1955264;   // N*64 floats (u)
constexpr size_t WS_ZERO_BYTES = 256 * 4;  // stats only

// ---- pass 1: per-chunk histogram over dst buckets ----
__global__ __launch_bounds__(256) void k_hist(const int* __restrict__ col,
                                              int* __restrict__ gh) {
    __shared__ int h[NBUCK_P];
    int c = blockIdx.x, t = threadIdx.x;
    for (int b = t; b < NBUCK_P; b += 256) h[b] = 0;
    __syncthreads();
    int e0 = c * CHUNK;
#pragma unroll
    for (int i = 0; i < CHUNK / 256; ++i) {
        int e = e0 + i * 256 + t;
        if (e < E_EDGES) atomicAdd(&h[col[e] >> BUCK_SHIFT], 1);
    }
    __syncthreads();
    for (int b = t; b < NBUCK_P; b += 256) gh[c * NBUCK_P + b] = h[b];
}

// ---- pass 2a: per-bucket exclusive scan over chunks; bucket totals ----
__global__ __launch_bounds__(256) void k_scan_buckets(int* __restrict__ gh,
                                                      int* __restrict__ base) {
    __shared__ int lds[256];
    int b = blockIdx.x, t = threadIdx.x;
    int v = (t < NCHUNK) ? gh[t * NBUCK_P + b] : 0;
    lds[t] = v;
    __syncthreads();
    int val = v;
#pragma unroll
    for (int off = 1; off < 256; off <<= 1) {
        int add = (t >= off) ? lds[t - off] : 0;
        __syncthreads();
        val += add;
        lds[t] = val;
        __syncthreads();
    }
    if (t < NCHUNK) gh[t * NBUCK_P + b] = val - v;  // exclusive within bucket
    if (t == 255) base[b] = val;                    // bucket total
}

// ---- pass 2b: exclusive scan of bucket totals -> bucket bases ----
__global__ __launch_bounds__(1024) void k_scan_bases(int* __restrict__ base,
                                                     int* __restrict__ rowptr) {
    __shared__ int lds[1024];
    int t = threadIdx.x;
    int v = (t < NBUCK) ? base[t] : 0;
    lds[t] = v;
    __syncthreads();
    int val = v;
#pragma unroll
    for (int off = 1; off < 1024; off <<= 1) {
        int add = (t >= off) ? lds[t - off] : 0;
        __syncthreads();
        val += add;
        lds[t] = val;
        __syncthreads();
    }
    if (t < NBUCK) base[t] = val - v;
    if (t == 1023) {
        base[NBUCK] = val;            // = E
        rowptr[N_NODES] = val;
    }
}

// ---- pass 3: scatter edges into bucket-contiguous array (packed 24-bit) ----
__global__ __launch_bounds__(256) void k_scatter_bin(const int* __restrict__ row,
                                                     const int* __restrict__ col,
                                                     const int* __restrict__ gh,
                                                     const int* __restrict__ base,
                                                     unsigned int* __restrict__ binned) {
    __shared__ int cur[NBUCK_P];
    int c = blockIdx.x, t = threadIdx.x;
    for (int b = t; b < NBUCK_P; b += 256) {
        int bb = (b < NBUCK) ? base[b] : 0;
        cur[b] = bb + gh[c * NBUCK_P + b];
    }
    __syncthreads();
    int e0 = c * CHUNK;
#pragma unroll
    for (int i = 0; i < CHUNK / 256; ++i) {
        int e = e0 + i * 256 + t;
        if (e < E_EDGES) {
            int d = col[e];
            int s = row[e];
            int p = atomicAdd(&cur[d >> BUCK_SHIFT], 1);
            binned[p] = ((unsigned int)(d & 127) << 17) | (unsigned int)s;
        }
    }
}

// ---- pass 4: per-bucket in-LDS counting sort -> csr (in place), rowptr, dinv ----
__global__ __launch_bounds__(256) void k_sortbucket(unsigned int* __restrict__ binned,
                                                    const int* __restrict__ base,
                                                    int* __restrict__ rowptr,
                                                    float* __restrict__ dinv) {
    __shared__ unsigned int ebuf[SORT_CAP];
    __shared__ int sbuf[SORT_CAP];
    __shared__ int lcnt[128];
    __shared__ int scanb[128];
    __shared__ int lptr[128];
    int b = blockIdx.x, t = threadIdx.x;
    int i0 = base[b], i1 = base[b + 1];
    int cnt = i1 - i0;
    if (cnt > SORT_CAP) cnt = SORT_CAP;  // statistically impossible
    int n0 = b << BUCK_SHIFT;
    int nn = min(128, N_NODES - n0);

    for (int k = t; k < cnt; k += 256) ebuf[k] = binned[i0 + k];
    if (t < 128) lcnt[t] = 0;
    __syncthreads();
    for (int k = t; k < cnt; k += 256) atomicAdd(&lcnt[ebuf[k] >> 17], 1);
    __syncthreads();

    // inclusive scan of lcnt over 128
    int myc = (t < 128) ? lcnt[t] : 0;
    if (t < 128) scanb[t] = myc;
    __syncthreads();
    int val = myc;
#pragma unroll
    for (int off = 1; off < 128; off <<= 1) {
        int add = (t < 128 && t >= off) ? scanb[t - off] : 0;
        __syncthreads();
        if (t < 128) {
            val += add;
            scanb[t] = val;
        }
        __syncthreads();
    }
    if (t < 128) {
        int excl = val - myc;
        lptr[t] = excl;
        if (t < nn) {
            rowptr[n0 + t] = i0 + excl;
            dinv[n0 + t] = rsqrtf((float)myc + 1.0f);  // +1 self loop
        }
    }
    __syncthreads();
    for (int k = t; k < cnt; k += 256) {
        unsigned int e = ebuf[k];
        int j = (int)(e >> 17);
        int p = atomicAdd(&lptr[j], 1);
        sbuf[p] = (int)(e & 0x1FFFF);
    }
    __syncthreads();
    for (int k = t; k < cnt; k += 256) binned[i0 + k] = (unsigned int)sbuf[k];  // csr in place
}

// ---- aggregation: 16 lanes per node, gather in-edges ----
// u[c] = dinv[c] * ( x[c]*dinv[c] + sum_{r->c} x[r]*dinv[r] )
__global__ __launch_bounds__(256) void k_agg(const float* __restrict__ x,
                                             const float* __restrict__ dinv,
                                             const int* __restrict__ rowptr,
                                             const unsigned int* __restrict__ csr,
                                             float* __restrict__ agg) {
    int t = blockIdx.x * blockDim.x + threadIdx.x;
    if (t >= N_NODES * 16) return;
    int c = t >> 4;
    int q = t & 15;
    float dc = dinv[c];
    float4 xv = ((const float4*)x)[(size_t)c * 16 + q];
    float4 acc;
    acc.x = xv.x * dc; acc.y = xv.y * dc; acc.z = xv.z * dc; acc.w = xv.w * dc;
    int i0 = rowptr[c], i1 = rowptr[c + 1];
    for (int i = i0; i < i1; ++i) {
        int s = (int)csr[i];
        float ds = dinv[s];
        float4 v = ((const float4*)x)[(size_t)s * 16 + q];
        acc.x += v.x * ds; acc.y += v.y * ds;
        acc.z += v.z * ds; acc.w += v.w * ds;
    }
    acc.x *= dc; acc.y *= dc; acc.z *= dc; acc.w *= dc;
    ((float4*)agg)[t] = acc;
}

// ---- fused GEMM: out_pre = [u|x] @ [W;skipW] + bias; per-column stats ----
#define BK 32
__global__ __launch_bounds__(256) void k_gemm(
    const float* __restrict__ u, const float* __restrict__ x,
    const float* __restrict__ W, const float* __restrict__ skipW,
    const float* __restrict__ bias, float* __restrict__ out,
    float* __restrict__ stats) {
    __shared__ float As[BK][128];
    __shared__ float Bs[BK][128];

    int ib = blockIdx.x * 128;
    int tid = threadIdx.x;
    int tx = tid & 15;
    int ty = tid >> 4;

    float acc[8][8];
#pragma unroll
    for (int a = 0; a < 8; ++a)
#pragma unroll
        for (int b = 0; b < 8; ++b) acc[a][b] = 0.0f;

    for (int kc = 0; kc < 128; kc += BK) {
        const float* asrc = (kc < 64) ? u : x;
        const float* bsrc = (kc < 64) ? W : skipW;
        int ksrc = (kc < 64) ? kc : (kc - 64);

#pragma unroll
        for (int p = 0; p < 4; ++p) {
            int i  = p * 32 + (tid >> 3);
            int kk = (tid & 7) * 4;
            float4 v = make_float4(0.f, 0.f, 0.f, 0.f);
            int gi = ib + i;
            if (gi < N_NODES)
                v = *(const float4*)&asrc[(size_t)gi * 64 + ksrc + kk];
            As[kk + 0][i] = v.x;
            As[kk + 1][i] = v.y;
            As[kk + 2][i] = v.z;
            As[kk + 3][i] = v.w;
        }
        {
            int kk = tid >> 3;
            int j0 = (tid & 7) * 16;
            const float* bp = &bsrc[(size_t)(ksrc + kk) * 128 + j0];
#pragma unroll
            for (int q = 0; q < 4; ++q)
                *(float4*)&Bs[kk][j0 + q * 4] = *(const float4*)&bp[q * 4];
        }
        __syncthreads();

#pragma unroll
        for (int kk = 0; kk < BK; ++kk) {
            float a[8], b[8];
            *(float4*)&a[0] = *(float4*)&As[kk][ty * 8];
            *(float4*)&a[4] = *(float4*)&As[kk][ty * 8 + 4];
            *(float4*)&b[0] = *(float4*)&Bs[kk][tx * 8];
            *(float4*)&b[4] = *(float4*)&Bs[kk][tx * 8 + 4];
#pragma unroll
            for (int ii = 0; ii < 8; ++ii)
#pragma unroll
                for (int jj = 0; jj < 8; ++jj) acc[ii][jj] += a[ii] * b[jj];
        }
        __syncthreads();
    }

    float bias8[8];
    *(float4*)&bias8[0] = *(const float4*)&bias[tx * 8];
    *(float4*)&bias8[4] = *(const float4*)&bias[tx * 8 + 4];

    float lsum[8], lsq[8];
#pragma unroll
    for (int jj = 0; jj < 8; ++jj) { lsum[jj] = 0.f; lsq[jj] = 0.f; }

#pragma unroll
    for (int ii = 0; ii < 8; ++ii) {
        int gi = ib + ty * 8 + ii;
        if (gi < N_NODES) {
            float vals[8];
#pragma unroll
            for (int jj = 0; jj < 8; ++jj) {
                float v = acc[ii][jj] + bias8[jj];
                vals[jj] = v;
                lsum[jj] += v;
                lsq[jj] += v * v;
            }
            *(float4*)&out[(size_t)gi * 128 + tx * 8]     = *(float4*)&vals[0];
            *(float4*)&out[(size_t)gi * 128 + tx * 8 + 4] = *(float4*)&vals[4];
        }
    }

    float* sred = &As[0][0];
    float* qred = &Bs[0][0];
#pragma unroll
    for (int jj = 0; jj < 8; ++jj) {
        sred[tid * 8 + jj] = lsum[jj];
        qred[tid * 8 + jj] = lsq[jj];
    }
    __syncthreads();
    if (tid < 128) {
        int j = tid;
        int txg = j >> 3, jj = j & 7;
        float s = 0.f, q = 0.f;
#pragma unroll
        for (int t2 = 0; t2 < 16; ++t2) {
            int st = t2 * 16 + txg;
            s += sred[st * 8 + jj];
            q += qred[st * 8 + jj];
        }
        atomicAdd(&stats[j], s);
        atomicAdd(&stats[128 + j], q);
    }
}

__global__ void k_finalize(const float* __restrict__ stats,
                           const float* __restrict__ gamma,
                           const float* __restrict__ beta,
                           float* __restrict__ scaleshift) {
    int j = threadIdx.x;
    if (j < 128) {
        float mean = stats[j] * (1.0f / N_NODES);
        float var  = stats[128 + j] * (1.0f / N_NODES) - mean * mean;
        float sc   = gamma[j] * rsqrtf(var + 1e-5f);
        scaleshift[j]       = sc;
        scaleshift[128 + j] = beta[j] - mean * sc;
    }
}

__global__ void k_apply(float* __restrict__ out, const float* __restrict__ scaleshift) {
    int t = blockIdx.x * blockDim.x + threadIdx.x;
    if (t >= N_NODES * 32) return;
    int j4 = t & 31;
    float4 v  = ((float4*)out)[t];
    float4 sc = ((const float4*)scaleshift)[j4];
    float4 sh = ((const float4*)(scaleshift + 128))[j4];
    v.x = fmaxf(fmaf(v.x, sc.x, sh.x), 0.f);
    v.y = fmaxf(fmaf(v.y, sc.y, sh.y), 0.f);
    v.z = fmaxf(fmaf(v.z, sc.z, sh.z), 0.f);
    v.w = fmaxf(fmaf(v.w, sc.w, sh.w), 0.f);
    ((float4*)out)[t] = v;
}

extern "C" void kernel_launch(void* const* d_in, const int* in_sizes, int n_in,
                              void* d_out, int out_size, void* d_ws, size_t ws_size,
                              hipStream_t stream) {
    const float* x      = (const float*)d_in[0];
    const int*   eidx   = (const int*)d_in[1];
    const float* W      = (const float*)d_in[2];
    const float* bias   = (const float*)d_in[3];
    const float* skipW  = (const float*)d_in[4];
    const float* gamma  = (const float*)d_in[5];
    const float* beta   = (const float*)d_in[6];
    float* out = (float*)d_out;
    float* ws  = (float*)d_ws;

    const int* row = eidx;
    const int* col = eidx + E_EDGES;

    float* stats      = ws + OFF_STATS;
    float* scaleshift = ws + OFF_SCALE;
    float* dinv       = ws + OFF_DINV;
    int*   rowptr     = (int*)(ws + OFF_ROWPTR);
    int*   base       = (int*)(ws + OFF_BASE);
    int*   gh         = (int*)(ws + OFF_GHIST);
    unsigned int* binned = (unsigned int*)(ws + OFF_BINNED);  // csr aliases after sort
    float* agg        = ws + OFF_AGG;

    hipMemsetAsync(d_ws, 0, WS_ZERO_BYTES, stream);

    k_hist<<<NCHUNK, 256, 0, stream>>>(col, gh);
    k_scan_buckets<<<NBUCK, 256, 0, stream>>>(gh, base);
    k_scan_bases<<<1, 1024, 0, stream>>>(base, rowptr);
    k_scatter_bin<<<NCHUNK, 256, 0, stream>>>(row, col, gh, base, binned);
    k_sortbucket<<<NBUCK, 256, 0, stream>>>(binned, base, rowptr, dinv);
    k_agg<<<(N_NODES * 16 + 255) / 256, 256, 0, stream>>>(x, dinv, rowptr, binned, agg);
    {
        int blocks = (N_NODES + 127) / 128;
        k_gemm<<<blocks, 256, 0, stream>>>(agg, x, W, skipW, bias, out, stats);
    }
    k_finalize<<<1, 128, 0, stream>>>(stats, gamma, beta, scaleshift);
    k_apply<<<(N_NODES * 32 + 255) / 256, 256, 0, stream>>>(out, scaleshift);
}

// Round 4
// 270.639 us; speedup vs baseline: 5.9997x; 1.0857x over previous
//
#include <hip/hip_runtime.h>

// GCN layer: out = ReLU(BN(GCNConv(x) + x@skip_W))
// R4: fp32 vector GEMM -> bf16 MFMA GEMM (LDS-free, direct global frags);
//     bf16 edge gather (halved L3 traffic). CSR build via counting sort (R3).

typedef unsigned short ushort;
typedef __bf16 bf16x8 __attribute__((ext_vector_type(8)));
typedef float f32x4 __attribute__((ext_vector_type(4)));

constexpr int N_NODES = 100000;
constexpr int N_PAD   = 100096;                  // 782*128
constexpr int E_EDGES = 1600000;

constexpr int BUCK_SHIFT = 7;                    // 128 nodes per bucket
constexpr int NBUCK   = (N_NODES + 127) / 128;   // 782
constexpr int NBUCK_P = 784;
constexpr int CHUNK   = 8192;
constexpr int NCHUNK  = (E_EDGES + CHUNK - 1) / CHUNK;  // 196
constexpr int SORT_CAP = 4096;

// ws layout (4-byte element offsets)
constexpr size_t OFF_STATS  = 0;         // 256 floats (zeroed)
constexpr size_t OFF_SCALE  = 256;       // 256 floats
constexpr size_t OFF_DINV   = 512;       // N floats
constexpr size_t OFF_ROWPTR = 100608;    // N+1 ints
constexpr size_t OFF_BASE   = 200704;    // NBUCK+1 ints
constexpr size_t OFF_GHIST  = 201536;    // NCHUNK*NBUCK_P = 153664 ints
constexpr size_t OFF_BINNED = 355264;    // E ints (packed edges; csr in place)
constexpr size_t OFF_BT     = 1955264;   // 128*128 ushort = 8192 floats
constexpr size_t OFF_XB     = 1963456;   // N_PAD*64 ushort = 3203072 floats
constexpr size_t OFF_CAT    = 5166528;   // N_PAD*128 ushort = 6406144 floats
constexpr size_t WS_ZERO_BYTES = 256 * 4;  // stats only

static __device__ __forceinline__ ushort f2bf(float f) {
    union { float f; unsigned u; } v; v.f = f;
    unsigned r = v.u + 0x7FFFu + ((v.u >> 16) & 1u);  // RNE
    return (ushort)(r >> 16);
}
static __device__ __forceinline__ float bf2f(ushort u) {
    union { unsigned u; float f; } v; v.u = (unsigned)u << 16;
    return v.f;
}

// ---- Bt[n][k] = bf16(B[k][n]), B = [W; skipW] ----
__global__ void k_prep(const float* __restrict__ W, const float* __restrict__ skipW,
                       ushort* __restrict__ Bt) {
    int t = blockIdx.x * 256 + threadIdx.x;
    if (t >= 128 * 128) return;
    int k = t >> 7, n = t & 127;
    float v = (k < 64) ? W[k * 128 + n] : skipW[(k - 64) * 128 + n];
    Bt[n * 128 + k] = f2bf(v);
}

// ---- xb = bf16(x); also fills cat[:,64:128] (pad rows zeroed) ----
__global__ void k_cast(const float* __restrict__ x, ushort* __restrict__ xb,
                       ushort* __restrict__ cat) {
    int t = blockIdx.x * blockDim.x + threadIdx.x;
    if (t >= N_PAD * 16) return;
    int c = t >> 4, q = t & 15;
    ushort4 b = {0, 0, 0, 0};
    if (c < N_NODES) {
        float4 v = ((const float4*)x)[t];
        b.x = f2bf(v.x); b.y = f2bf(v.y); b.z = f2bf(v.z); b.w = f2bf(v.w);
    }
    ((ushort4*)xb)[t] = b;
    *(ushort4*)&cat[(size_t)c * 128 + 64 + q * 4] = b;
}

// ---- pass 1: per-chunk histogram over dst buckets ----
__global__ __launch_bounds__(256) void k_hist(const int* __restrict__ col,
                                              int* __restrict__ gh) {
    __shared__ int h[NBUCK_P];
    int c = blockIdx.x, t = threadIdx.x;
    for (int b = t; b < NBUCK_P; b += 256) h[b] = 0;
    __syncthreads();
    int e0 = c * CHUNK;
#pragma unroll
    for (int i = 0; i < CHUNK / 256; ++i) {
        int e = e0 + i * 256 + t;
        if (e < E_EDGES) atomicAdd(&h[col[e] >> BUCK_SHIFT], 1);
    }
    __syncthreads();
    for (int b = t; b < NBUCK_P; b += 256) gh[c * NBUCK_P + b] = h[b];
}

// ---- pass 2a: per-bucket exclusive scan over chunks; bucket totals ----
__global__ __launch_bounds__(256) void k_scan_buckets(int* __restrict__ gh,
                                                      int* __restrict__ base) {
    __shared__ int lds[256];
    int b = blockIdx.x, t = threadIdx.x;
    int v = (t < NCHUNK) ? gh[t * NBUCK_P + b] : 0;
    lds[t] = v;
    __syncthreads();
    int val = v;
#pragma unroll
    for (int off = 1; off < 256; off <<= 1) {
        int add = (t >= off) ? lds[t - off] : 0;
        __syncthreads();
        val += add;
        lds[t] = val;
        __syncthreads();
    }
    if (t < NCHUNK) gh[t * NBUCK_P + b] = val - v;
    if (t == 255) base[b] = val;
}

// ---- pass 2b: exclusive scan of bucket totals -> bucket bases ----
__global__ __launch_bounds__(1024) void k_scan_bases(int* __restrict__ base,
                                                     int* __restrict__ rowptr) {
    __shared__ int lds[1024];
    int t = threadIdx.x;
    int v = (t < NBUCK) ? base[t] : 0;
    lds[t] = v;
    __syncthreads();
    int val = v;
#pragma unroll
    for (int off = 1; off < 1024; off <<= 1) {
        int add = (t >= off) ? lds[t - off] : 0;
        __syncthreads();
        val += add;
        lds[t] = val;
        __syncthreads();
    }
    if (t < NBUCK) base[t] = val - v;
    if (t == 1023) {
        base[NBUCK] = val;
        rowptr[N_NODES] = val;
    }
}

// ---- pass 3: scatter edges into bucket-contiguous array (packed) ----
__global__ __launch_bounds__(256) void k_scatter_bin(const int* __restrict__ row,
                                                     const int* __restrict__ col,
                                                     const int* __restrict__ gh,
                                                     const int* __restrict__ base,
                                                     unsigned int* __restrict__ binned) {
    __shared__ int cur[NBUCK_P];
    int c = blockIdx.x, t = threadIdx.x;
    for (int b = t; b < NBUCK_P; b += 256) {
        int bb = (b < NBUCK) ? base[b] : 0;
        cur[b] = bb + gh[c * NBUCK_P + b];
    }
    __syncthreads();
    int e0 = c * CHUNK;
#pragma unroll
    for (int i = 0; i < CHUNK / 256; ++i) {
        int e = e0 + i * 256 + t;
        if (e < E_EDGES) {
            int d = col[e];
            int s = row[e];
            int p = atomicAdd(&cur[d >> BUCK_SHIFT], 1);
            binned[p] = ((unsigned int)(d & 127) << 17) | (unsigned int)s;
        }
    }
}

// ---- pass 4: per-bucket in-LDS counting sort -> csr, rowptr, dinv ----
__global__ __launch_bounds__(256) void k_sortbucket(unsigned int* __restrict__ binned,
                                                    const int* __restrict__ base,
                                                    int* __restrict__ rowptr,
                                                    float* __restrict__ dinv) {
    __shared__ unsigned int ebuf[SORT_CAP];
    __shared__ int sbuf[SORT_CAP];
    __shared__ int lcnt[128];
    __shared__ int scanb[128];
    __shared__ int lptr[128];
    int b = blockIdx.x, t = threadIdx.x;
    int i0 = base[b], i1 = base[b + 1];
    int cnt = i1 - i0;
    if (cnt > SORT_CAP) cnt = SORT_CAP;
    int n0 = b << BUCK_SHIFT;
    int nn = min(128, N_NODES - n0);

    for (int k = t; k < cnt; k += 256) ebuf[k] = binned[i0 + k];
    if (t < 128) lcnt[t] = 0;
    __syncthreads();
    for (int k = t; k < cnt; k += 256) atomicAdd(&lcnt[ebuf[k] >> 17], 1);
    __syncthreads();

    int myc = (t < 128) ? lcnt[t] : 0;
    if (t < 128) scanb[t] = myc;
    __syncthreads();
    int val = myc;
#pragma unroll
    for (int off = 1; off < 128; off <<= 1) {
        int add = (t < 128 && t >= off) ? scanb[t - off] : 0;
        __syncthreads();
        if (t < 128) {
            val += add;
            scanb[t] = val;
        }
        __syncthreads();
    }
    if (t < 128) {
        int excl = val - myc;
        lptr[t] = excl;
        if (t < nn) {
            rowptr[n0 + t] = i0 + excl;
            dinv[n0 + t] = rsqrtf((float)myc + 1.0f);  // +1 self loop
        }
    }
    __syncthreads();
    for (int k = t; k < cnt; k += 256) {
        unsigned int e = ebuf[k];
        int j = (int)(e >> 17);
        int p = atomicAdd(&lptr[j], 1);
        sbuf[p] = (int)(e & 0x1FFFF);
    }
    __syncthreads();
    for (int k = t; k < cnt; k += 256) binned[i0 + k] = (unsigned int)sbuf[k];
}

// ---- aggregation (bf16 gather): cat[:,0:64] = bf16(u) ----
// u[c] = dinv[c] * ( xb[c]*dinv[c] + sum_{r->c} xb[r]*dinv[r] )
__global__ __launch_bounds__(256) void k_agg(const ushort* __restrict__ xb,
                                             const float* __restrict__ dinv,
                                             const int* __restrict__ rowptr,
                                             const unsigned int* __restrict__ csr,
                                             ushort* __restrict__ cat) {
    int t = blockIdx.x * blockDim.x + threadIdx.x;
    if (t >= N_PAD * 16) return;
    int c = t >> 4;
    int q = t & 15;
    if (c >= N_NODES) {
        ushort4 z = {0, 0, 0, 0};
        *(ushort4*)&cat[(size_t)c * 128 + q * 4] = z;
        return;
    }
    float dc = dinv[c];
    ushort4 xv = ((const ushort4*)xb)[t];
    float4 acc;
    acc.x = bf2f(xv.x) * dc; acc.y = bf2f(xv.y) * dc;
    acc.z = bf2f(xv.z) * dc; acc.w = bf2f(xv.w) * dc;
    int i0 = rowptr[c], i1 = rowptr[c + 1];
    for (int i = i0; i < i1; ++i) {
        int s = (int)csr[i];
        float ds = dinv[s];
        ushort4 v = ((const ushort4*)xb)[s * 16 + q];
        acc.x += bf2f(v.x) * ds; acc.y += bf2f(v.y) * ds;
        acc.z += bf2f(v.z) * ds; acc.w += bf2f(v.w) * ds;
    }
    ushort4 o;
    o.x = f2bf(acc.x * dc); o.y = f2bf(acc.y * dc);
    o.z = f2bf(acc.z * dc); o.w = f2bf(acc.w * dc);
    *(ushort4*)&cat[(size_t)c * 128 + q * 4] = o;
}

// ---- MFMA GEMM: out_pre = cat @ Bt^T + bias; per-column stats ----
// LDS-free: A/B fragments loaded directly global->VGPR (16B contiguous each).
// Block = 4 waves = 128 rows; each wave 64x64 (4x4 tiles of 16x16x32 bf16).
__global__ __launch_bounds__(256) void k_gemm(const ushort* __restrict__ cat,
                                              const ushort* __restrict__ Bt,
                                              const float* __restrict__ bias,
                                              float* __restrict__ out,
                                              float* __restrict__ stats) {
    __shared__ float sred[128];
    __shared__ float qred[128];
    int tid = threadIdx.x;
    int wave = tid >> 6, lane = tid & 63;
    int wm = wave >> 1, wn = wave & 1;
    int l15 = lane & 15, quad = lane >> 4;
    int row0 = blockIdx.x * 128 + wm * 64;
    int col0 = wn * 64;

    if (tid < 128) { sred[tid] = 0.f; qred[tid] = 0.f; }
    __syncthreads();

    f32x4 acc[4][4];
#pragma unroll
    for (int a = 0; a < 4; ++a)
#pragma unroll
        for (int b = 0; b < 4; ++b) acc[a][b] = (f32x4){0.f, 0.f, 0.f, 0.f};

    const ushort* ap[4];
    const ushort* bp[4];
#pragma unroll
    for (int im = 0; im < 4; ++im)
        ap[im] = cat + (size_t)(row0 + im * 16 + l15) * 128 + quad * 8;
#pragma unroll
    for (int jn = 0; jn < 4; ++jn)
        bp[jn] = Bt + (size_t)(col0 + jn * 16 + l15) * 128 + quad * 8;

#pragma unroll
    for (int kc = 0; kc < 4; ++kc) {
        bf16x8 a[4], b[4];
#pragma unroll
        for (int im = 0; im < 4; ++im) a[im] = *(const bf16x8*)(ap[im] + kc * 32);
#pragma unroll
        for (int jn = 0; jn < 4; ++jn) b[jn] = *(const bf16x8*)(bp[jn] + kc * 32);
#pragma unroll
        for (int im = 0; im < 4; ++im)
#pragma unroll
            for (int jn = 0; jn < 4; ++jn)
                acc[im][jn] = __builtin_amdgcn_mfma_f32_16x16x32_bf16(
                    a[im], b[jn], acc[im][jn], 0, 0, 0);
    }

    // epilogue: +bias, store, column stats
    int coln[4];
    float bi[4];
#pragma unroll
    for (int jn = 0; jn < 4; ++jn) {
        coln[jn] = col0 + jn * 16 + l15;
        bi[jn] = bias[coln[jn]];
    }
    float lsum[4] = {0.f, 0.f, 0.f, 0.f};
    float lsq[4]  = {0.f, 0.f, 0.f, 0.f};
#pragma unroll
    for (int im = 0; im < 4; ++im) {
        int rbase = row0 + im * 16 + quad * 4;
#pragma unroll
        for (int r = 0; r < 4; ++r) {
            int rowi = rbase + r;
            if (rowi < N_NODES) {
#pragma unroll
                for (int jn = 0; jn < 4; ++jn) {
                    float v = acc[im][jn][r] + bi[jn];
                    out[(size_t)rowi * 128 + coln[jn]] = v;
                    lsum[jn] += v;
                    lsq[jn]  += v * v;
                }
            }
        }
    }
#pragma unroll
    for (int jn = 0; jn < 4; ++jn) {
        atomicAdd(&sred[coln[jn]], lsum[jn]);
        atomicAdd(&qred[coln[jn]], lsq[jn]);
    }
    __syncthreads();
    if (tid < 128) {
        atomicAdd(&stats[tid], sred[tid]);
        atomicAdd(&stats[128 + tid], qred[tid]);
    }
}

__global__ void k_finalize(const float* __restrict__ stats,
                           const float* __restrict__ gamma,
                           const float* __restrict__ beta,
                           float* __restrict__ scaleshift) {
    int j = threadIdx.x;
    if (j < 128) {
        float mean = stats[j] * (1.0f / N_NODES);
        float var  = stats[128 + j] * (1.0f / N_NODES) - mean * mean;
        float sc   = gamma[j] * rsqrtf(var + 1e-5f);
        scaleshift[j]       = sc;
        scaleshift[128 + j] = beta[j] - mean * sc;
    }
}

__global__ void k_apply(float* __restrict__ out, const float* __restrict__ scaleshift) {
    int t = blockIdx.x * blockDim.x + threadIdx.x;
    if (t >= N_NODES * 32) return;
    int j4 = t & 31;
    float4 v  = ((float4*)out)[t];
    float4 sc = ((const float4*)scaleshift)[j4];
    float4 sh = ((const float4*)(scaleshift + 128))[j4];
    v.x = fmaxf(fmaf(v.x, sc.x, sh.x), 0.f);
    v.y = fmaxf(fmaf(v.y, sc.y, sh.y), 0.f);
    v.z = fmaxf(fmaf(v.z, sc.z, sh.z), 0.f);
    v.w = fmaxf(fmaf(v.w, sc.w, sh.w), 0.f);
    ((float4*)out)[t] = v;
}

extern "C" void kernel_launch(void* const* d_in, const int* in_sizes, int n_in,
                              void* d_out, int out_size, void* d_ws, size_t ws_size,
                              hipStream_t stream) {
    const float* x      = (const float*)d_in[0];
    const int*   eidx   = (const int*)d_in[1];
    const float* W      = (const float*)d_in[2];
    const float* bias   = (const float*)d_in[3];
    const float* skipW  = (const float*)d_in[4];
    const float* gamma  = (const float*)d_in[5];
    const float* beta   = (const float*)d_in[6];
    float* out = (float*)d_out;
    float* ws  = (float*)d_ws;

    const int* row = eidx;
    const int* col = eidx + E_EDGES;

    float* stats      = ws + OFF_STATS;
    float* scaleshift = ws + OFF_SCALE;
    float* dinv       = ws + OFF_DINV;
    int*   rowptr     = (int*)(ws + OFF_ROWPTR);
    int*   base       = (int*)(ws + OFF_BASE);
    int*   gh         = (int*)(ws + OFF_GHIST);
    unsigned int* binned = (unsigned int*)(ws + OFF_BINNED);
    ushort* Bt        = (ushort*)(ws + OFF_BT);
    ushort* xb        = (ushort*)(ws + OFF_XB);
    ushort* cat       = (ushort*)(ws + OFF_CAT);

    hipMemsetAsync(d_ws, 0, WS_ZERO_BYTES, stream);

    k_prep<<<64, 256, 0, stream>>>(W, skipW, Bt);
    k_cast<<<(N_PAD * 16 + 255) / 256, 256, 0, stream>>>(x, xb, cat);
    k_hist<<<NCHUNK, 256, 0, stream>>>(col, gh);
    k_scan_buckets<<<NBUCK, 256, 0, stream>>>(gh, base);
    k_scan_bases<<<1, 1024, 0, stream>>>(base, rowptr);
    k_scatter_bin<<<NCHUNK, 256, 0, stream>>>(row, col, gh, base, binned);
    k_sortbucket<<<NBUCK, 256, 0, stream>>>(binned, base, rowptr, dinv);
    k_agg<<<(N_PAD * 16 + 255) / 256, 256, 0, stream>>>(xb, dinv, rowptr, binned, cat);
    k_gemm<<<NBUCK, 256, 0, stream>>>(cat, Bt, bias, out, stats);
    k_finalize<<<1, 128, 0, stream>>>(stats, gamma, beta, scaleshift);
    k_apply<<<(N_NODES * 32 + 255) / 256, 256, 0, stream>>>(out, scaleshift);
}